// Round 1
// baseline (1205.032 us; speedup 1.0000x reference)
//
#include <hip/hip_runtime.h>
#include <math.h>

// DeeperGCN on MI355X. N=50000, E=625000, D=128, L=7.
// Strategy: CSR-by-dst build per call, online-softmax single-pass aggregation
// (wave per node), fp32 register-tiled GEMM, LN as wave-per-node kernel.

constexpr int D = 128;
constexpr int NA = 9;   // atom feats
constexpr int NB = 3;   // bond feats

// ------------------------- CSR build -------------------------

__global__ void k_hist(const int* __restrict__ dst, int* __restrict__ deg, int E) {
    int e = blockIdx.x * 256 + threadIdx.x;
    if (e < E) atomicAdd(&deg[dst[e]], 1);
}

__global__ void k_scan_a(const int* __restrict__ deg, int* __restrict__ offs,
                         int* __restrict__ bsum, int N) {
    __shared__ int s[256];
    int i = blockIdx.x * 256 + threadIdx.x;
    int v = (i < N) ? deg[i] : 0;
    s[threadIdx.x] = v;
    __syncthreads();
    for (int d = 1; d < 256; d <<= 1) {
        int add = (threadIdx.x >= d) ? s[threadIdx.x - d] : 0;
        __syncthreads();
        s[threadIdx.x] += add;
        __syncthreads();
    }
    if (i < N) offs[i + 1] = s[threadIdx.x];
    if (threadIdx.x == 255) bsum[blockIdx.x] = s[255];
    if (i == 0) offs[0] = 0;
}

// nb must be <= 256 (N=50000 -> nb=196)
__global__ void k_scan_b(const int* __restrict__ bsum, int* __restrict__ bexc, int nb) {
    __shared__ int s[256];
    int t = threadIdx.x;
    int v = (t < nb) ? bsum[t] : 0;
    s[t] = v;
    __syncthreads();
    for (int d = 1; d < 256; d <<= 1) {
        int add = (t >= d) ? s[t - d] : 0;
        __syncthreads();
        s[t] += add;
        __syncthreads();
    }
    if (t < nb) bexc[t] = s[t] - v;  // exclusive block prefix
}

__global__ void k_scan_c(int* __restrict__ offs, const int* __restrict__ bexc, int N) {
    int i = blockIdx.x * 256 + threadIdx.x;
    if (i < N) offs[i + 1] += bexc[blockIdx.x];
}

__global__ void k_fill(const int* __restrict__ src, const int* __restrict__ dst,
                       const int* __restrict__ attr, const int* __restrict__ offs,
                       int* __restrict__ cur, int4* __restrict__ recs, int E) {
    int e = blockIdx.x * 256 + threadIdx.x;
    if (e >= E) return;
    int d = dst[e];
    int pos = offs[d] + atomicAdd(&cur[d], 1);
    recs[pos] = make_int4(src[e], attr[e * 3], attr[e * 3 + 1], attr[e * 3 + 2]);
}

// ------------------------- Atom encoder -------------------------
// wave per node; lane holds d = 2*lane, 2*lane+1

__global__ void k_atom(const int* __restrict__ x, const float* __restrict__ aemb,
                       float* __restrict__ h, int N) {
    int wid = (blockIdx.x * blockDim.x + threadIdx.x) >> 6;
    int lane = threadIdx.x & 63;
    if (wid >= N) return;
    const int* xr = x + wid * NA;
    float ax = 0.f, ay = 0.f;
#pragma unroll
    for (int f = 0; f < NA; ++f) {
        int v = xr[f];  // wave-uniform broadcast
        const float2 e = *(const float2*)(aemb + (f * 64 + v) * D + 2 * lane);
        ax += e.x; ay += e.y;
    }
    *(float2*)(h + wid * D + 2 * lane) = make_float2(ax, ay);
}

// ------------------------- LayerNorm (+optional ReLU) -------------------------

template <bool RELU>
__global__ void k_ln(const float* __restrict__ in, const float* __restrict__ g,
                     const float* __restrict__ bta, float* __restrict__ out, int N) {
    int wid = (blockIdx.x * blockDim.x + threadIdx.x) >> 6;
    int lane = threadIdx.x & 63;
    if (wid >= N) return;
    float2 v = *(const float2*)(in + wid * D + 2 * lane);
    float s = v.x + v.y;
    float ss = v.x * v.x + v.y * v.y;
#pragma unroll
    for (int o = 32; o > 0; o >>= 1) {
        s += __shfl_xor(s, o, 64);
        ss += __shfl_xor(ss, o, 64);
    }
    float mu = s * (1.f / 128.f);
    float var = ss * (1.f / 128.f) - mu * mu;
    float rs = rsqrtf(var + 1e-5f);
    float2 gg = *(const float2*)(g + 2 * lane);
    float2 bb = *(const float2*)(bta + 2 * lane);
    float ox = (v.x - mu) * rs * gg.x + bb.x;
    float oy = (v.y - mu) * rs * gg.y + bb.y;
    if (RELU) { ox = fmaxf(ox, 0.f); oy = fmaxf(oy, 0.f); }
    *(float2*)(out + wid * D + 2 * lane) = make_float2(ox, oy);
}

// ------------------------- Aggregation (online softmax) -------------------------
// wave per node; t[n] = hconv[n] + m[n]

__global__ void k_agg(const float* __restrict__ hconv, const int4* __restrict__ recs,
                      const int* __restrict__ offs, const float* __restrict__ bemb,
                      float* __restrict__ t, int N) {
    __shared__ float sb[NB * 8 * D];  // 3072 floats = 12 KB
    for (int i = threadIdx.x; i < NB * 8 * D; i += 256) sb[i] = bemb[i];
    __syncthreads();
    int wid = (blockIdx.x * blockDim.x + threadIdx.x) >> 6;
    int lane = threadIdx.x & 63;
    if (wid >= N) return;
    int start = offs[wid], end = offs[wid + 1];
    int dl = 2 * lane;

    float Mx = -INFINITY, My = -INFINITY;
    float Sx = 0.f, Sy = 0.f, Wx = 0.f, Wy = 0.f;

    int4 r;
    float2 hv;
    if (start < end) {
        r = recs[start];
        hv = *(const float2*)(hconv + r.x * D + dl);
    }
    for (int e = start; e < end; ++e) {
        int4 rn; float2 hn;
        if (e + 1 < end) {  // prefetch next edge (hide rec->gather latency)
            rn = recs[e + 1];
            hn = *(const float2*)(hconv + rn.x * D + dl);
        }
        float2 b0 = *(const float2*)(sb + r.y * D + dl);
        float2 b1 = *(const float2*)(sb + 1024 + r.z * D + dl);
        float2 b2 = *(const float2*)(sb + 2048 + r.w * D + dl);
        float vx = fmaxf(hv.x + b0.x + b1.x + b2.x, 0.f) + 1e-7f;
        float vy = fmaxf(hv.y + b0.y + b1.y + b2.y, 0.f) + 1e-7f;
        // online softmax update (expf(-inf)=0 handles first iteration)
        float nM = fmaxf(Mx, vx);
        float c = __expf(Mx - nM);
        float p = __expf(vx - nM);
        Sx = Sx * c + p; Wx = Wx * c + p * vx; Mx = nM;
        nM = fmaxf(My, vy);
        c = __expf(My - nM);
        p = __expf(vy - nM);
        Sy = Sy * c + p; Wy = Wy * c + p * vy; My = nM;
        r = rn; hv = hn;
    }
    float mx = Wx / (Sx + 1e-16f);
    float my = Wy / (Sy + 1e-16f);
    float2 hme = *(const float2*)(hconv + wid * D + dl);
    *(float2*)(t + wid * D + dl) = make_float2(hme.x + mx, hme.y + my);
}

// ------------------------- GEMM: out = t @ W + b (+ res) -------------------------
// 128-node tile, 256 threads, 8x8 micro-tile per thread, fp32 VALU.

__global__ __launch_bounds__(256) void k_gemm(const float* __restrict__ A,
                                              const float* __restrict__ Wl,
                                              const float* __restrict__ bl,
                                              const float* __restrict__ res,
                                              float* __restrict__ out, int N, int useRes) {
    __shared__ float As[128 * 36];  // [m][k] padded stride 36 (16B-aligned rows)
    __shared__ float Bs[32 * 128];  // [k][j]
    int tid = threadIdx.x;
    int tx = tid & 15;   // j-group: outputs tx*8 .. tx*8+7
    int ty = tid >> 4;   // m-group: nodes ty + 16*i, i=0..7
    int m0 = blockIdx.x * 128;

    float acc[8][8];
#pragma unroll
    for (int i = 0; i < 8; ++i)
#pragma unroll
        for (int j = 0; j < 8; ++j) acc[i][j] = 0.f;

    for (int kk0 = 0; kk0 < 128; kk0 += 32) {
#pragma unroll
        for (int it = 0; it < 4; ++it) {  // stage A chunk: 128x32
            int lin = it * 256 + tid;
            int node = lin >> 3, kq = lin & 7;
            int gm = m0 + node;
            float4 va = (gm < N) ? *(const float4*)(A + gm * 128 + kk0 + kq * 4)
                                 : make_float4(0.f, 0.f, 0.f, 0.f);
            *(float4*)(As + node * 36 + kq * 4) = va;
        }
#pragma unroll
        for (int it = 0; it < 4; ++it) {  // stage B chunk: 32x128
            int lin = it * 256 + tid;
            int k = lin >> 5, jq = lin & 31;
            *(float4*)(Bs + k * 128 + jq * 4) = *(const float4*)(Wl + (kk0 + k) * 128 + jq * 4);
        }
        __syncthreads();
#pragma unroll
        for (int kk = 0; kk < 32; ++kk) {
            float4 b0 = *(const float4*)(Bs + kk * 128 + tx * 8);
            float4 b1 = *(const float4*)(Bs + kk * 128 + tx * 8 + 4);
            float av[8];
#pragma unroll
            for (int i = 0; i < 8; ++i) av[i] = As[(ty + 16 * i) * 36 + kk];
#pragma unroll
            for (int i = 0; i < 8; ++i) {
                float a = av[i];
                acc[i][0] = fmaf(a, b0.x, acc[i][0]);
                acc[i][1] = fmaf(a, b0.y, acc[i][1]);
                acc[i][2] = fmaf(a, b0.z, acc[i][2]);
                acc[i][3] = fmaf(a, b0.w, acc[i][3]);
                acc[i][4] = fmaf(a, b1.x, acc[i][4]);
                acc[i][5] = fmaf(a, b1.y, acc[i][5]);
                acc[i][6] = fmaf(a, b1.z, acc[i][6]);
                acc[i][7] = fmaf(a, b1.w, acc[i][7]);
            }
        }
        __syncthreads();
    }

    float4 bb0 = *(const float4*)(bl + tx * 8);
    float4 bb1 = *(const float4*)(bl + tx * 8 + 4);
#pragma unroll
    for (int i = 0; i < 8; ++i) {
        int gm = m0 + ty + 16 * i;
        if (gm >= N) continue;
        float o[8];
#pragma unroll
        for (int j = 0; j < 8; ++j) o[j] = acc[i][j];
        o[0] += bb0.x; o[1] += bb0.y; o[2] += bb0.z; o[3] += bb0.w;
        o[4] += bb1.x; o[5] += bb1.y; o[6] += bb1.z; o[7] += bb1.w;
        if (useRes) {
            float4 r0 = *(const float4*)(res + gm * 128 + tx * 8);
            float4 r1 = *(const float4*)(res + gm * 128 + tx * 8 + 4);
            o[0] += r0.x; o[1] += r0.y; o[2] += r0.z; o[3] += r0.w;
            o[4] += r1.x; o[5] += r1.y; o[6] += r1.z; o[7] += r1.w;
        }
        *(float4*)(out + gm * 128 + tx * 8) = make_float4(o[0], o[1], o[2], o[3]);
        *(float4*)(out + gm * 128 + tx * 8 + 4) = make_float4(o[4], o[5], o[6], o[7]);
    }
}

// ------------------------- Launch -------------------------

extern "C" void kernel_launch(void* const* d_in, const int* in_sizes, int n_in,
                              void* d_out, int out_size, void* d_ws, size_t ws_size,
                              hipStream_t stream) {
    const int*   x    = (const int*)d_in[0];
    const int*   ei   = (const int*)d_in[1];
    const int*   attr = (const int*)d_in[2];
    const float* aemb = (const float*)d_in[3];
    const float* bemb = (const float*)d_in[4];
    const float* Wf   = (const float*)d_in[5];
    const float* bf   = (const float*)d_in[6];
    const float* gam  = (const float*)d_in[7];
    const float* bet  = (const float*)d_in[8];
    float* out = (float*)d_out;

    const int N = in_sizes[0] / NA;        // 50000
    const int E = in_sizes[1] / 2;         // 625000
    const int L = in_sizes[5] / (D * D);   // 7

    char* ws = (char*)d_ws;
    size_t o = 0;
    auto carve = [&](size_t bytes) -> void* {
        void* p = (void*)(ws + o);
        o += (bytes + 255) & ~(size_t)255;
        return p;
    };
    float* h     = (float*)carve((size_t)N * D * 4);
    float* hconv = (float*)carve((size_t)N * D * 4);
    float* t     = (float*)carve((size_t)N * D * 4);
    int4*  recs  = (int4*)carve((size_t)E * 16);
    int*   deg   = (int*)carve((size_t)N * 4);
    int*   cur   = (int*)carve((size_t)N * 4);
    int*   offs  = (int*)carve((size_t)(N + 1) * 4);
    int*   bsum  = (int*)carve(4096);
    int*   bexc  = (int*)carve(4096);

    const int* src = ei;
    const int* dst = ei + E;

    hipMemsetAsync(deg, 0, (size_t)N * 4, stream);
    hipMemsetAsync(cur, 0, (size_t)N * 4, stream);

    int ebl = (E + 255) / 256;
    int nbl = (N + 255) / 256;  // 196 (<=256 required by k_scan_b)
    k_hist<<<ebl, 256, 0, stream>>>(dst, deg, E);
    k_scan_a<<<nbl, 256, 0, stream>>>(deg, offs, bsum, N);
    k_scan_b<<<1, 256, 0, stream>>>(bsum, bexc, nbl);
    k_scan_c<<<nbl, 256, 0, stream>>>(offs, bexc, N);
    k_fill<<<ebl, 256, 0, stream>>>(src, dst, attr, offs, cur, recs, E);

    int wbl = (N * 64 + 255) / 256;  // wave per node, 4 waves/block
    k_atom<<<wbl, 256, 0, stream>>>(x, aemb, h, N);

    int gbl = (N + 127) / 128;
    for (int l = 0; l < L; ++l) {
        const float* hc;
        if (l == 0) {
            hc = h;
        } else {
            k_ln<true><<<wbl, 256, 0, stream>>>(h, gam + (l - 1) * D, bet + (l - 1) * D, hconv, N);
            hc = hconv;
        }
        k_agg<<<wbl, 256, 0, stream>>>(hc, recs, offs, bemb, t, N);
        k_gemm<<<gbl, 256, 0, stream>>>(t, Wf + l * D * D, bf + l * D, h, h, N, l > 0 ? 1 : 0);
    }
    k_ln<false><<<wbl, 256, 0, stream>>>(h, gam + (L - 1) * D, bet + (L - 1) * D, out, N);
}

// Round 2
// 843.413 us; speedup vs baseline: 1.4288x; 1.4288x over previous
//
#include <hip/hip_runtime.h>
#include <math.h>

// DeeperGCN on MI355X. N=50000, E=625000, D=128, L=7.
// CSR-by-dst build per call; online-softmax single-pass aggregation
// (wave per node, pairwise edge processing, scalar record loads);
// fp32 register-tiled GEMM with fused LayerNorm(+ReLU) epilogue.

constexpr int D = 128;
constexpr int NA = 9;   // atom feats
constexpr int NB = 3;   // bond feats

// ------------------------- CSR build -------------------------

__global__ void k_hist(const int* __restrict__ dst, int* __restrict__ deg, int E) {
    int e = blockIdx.x * 256 + threadIdx.x;
    if (e < E) atomicAdd(&deg[dst[e]], 1);
}

__global__ void k_scan_a(const int* __restrict__ deg, int* __restrict__ offs,
                         int* __restrict__ bsum, int N) {
    __shared__ int s[256];
    int i = blockIdx.x * 256 + threadIdx.x;
    int v = (i < N) ? deg[i] : 0;
    s[threadIdx.x] = v;
    __syncthreads();
    for (int d = 1; d < 256; d <<= 1) {
        int add = (threadIdx.x >= d) ? s[threadIdx.x - d] : 0;
        __syncthreads();
        s[threadIdx.x] += add;
        __syncthreads();
    }
    if (i < N) offs[i + 1] = s[threadIdx.x];
    if (threadIdx.x == 255) bsum[blockIdx.x] = s[255];
    if (i == 0) offs[0] = 0;
}

// nb must be <= 256 (N=50000 -> nb=196)
__global__ void k_scan_b(const int* __restrict__ bsum, int* __restrict__ bexc, int nb) {
    __shared__ int s[256];
    int t = threadIdx.x;
    int v = (t < nb) ? bsum[t] : 0;
    s[t] = v;
    __syncthreads();
    for (int d = 1; d < 256; d <<= 1) {
        int add = (t >= d) ? s[t - d] : 0;
        __syncthreads();
        s[t] += add;
        __syncthreads();
    }
    if (t < nb) bexc[t] = s[t] - v;  // exclusive block prefix
}

__global__ void k_scan_c(int* __restrict__ offs, const int* __restrict__ bexc, int N) {
    int i = blockIdx.x * 256 + threadIdx.x;
    if (i < N) offs[i + 1] += bexc[blockIdx.x];
}

__global__ void k_fill(const int* __restrict__ src, const int* __restrict__ dst,
                       const int* __restrict__ attr, const int* __restrict__ offs,
                       int* __restrict__ cur, int4* __restrict__ recs, int E) {
    int e = blockIdx.x * 256 + threadIdx.x;
    if (e >= E) return;
    int d = dst[e];
    int pos = offs[d] + atomicAdd(&cur[d], 1);
    recs[pos] = make_int4(src[e], attr[e * 3], attr[e * 3 + 1], attr[e * 3 + 2]);
}

// ------------------------- Atom encoder -------------------------
// wave per node; lane holds d = 2*lane, 2*lane+1

__global__ void k_atom(const int* __restrict__ x, const float* __restrict__ aemb,
                       float* __restrict__ h, int N) {
    int wid = (blockIdx.x * blockDim.x + threadIdx.x) >> 6;
    int lane = threadIdx.x & 63;
    if (wid >= N) return;
    const int* xr = x + wid * NA;
    float ax = 0.f, ay = 0.f;
#pragma unroll
    for (int f = 0; f < NA; ++f) {
        int v = xr[f];  // wave-uniform broadcast
        const float2 e = *(const float2*)(aemb + (f * 64 + v) * D + 2 * lane);
        ax += e.x; ay += e.y;
    }
    *(float2*)(h + wid * D + 2 * lane) = make_float2(ax, ay);
}

// ------------------------- Aggregation (online softmax, pairwise) -------------------------
// wave per node; t[n] = hconv[n] + m[n]. Block = 1024 (16 nodes) to amortize
// the 12KB bemb->LDS staging. Edge records scalar-loaded (uniform loop).

__global__ __launch_bounds__(1024) void k_agg(const float* __restrict__ hconv,
                      const int4* __restrict__ recs,
                      const int* __restrict__ offs, const float* __restrict__ bemb,
                      float* __restrict__ t, int N) {
    __shared__ float sb[NB * 8 * D];  // 3072 floats = 12 KB
    for (int i = threadIdx.x; i < NB * 8 * D; i += 1024) sb[i] = bemb[i];
    __syncthreads();
    int wid = (blockIdx.x * blockDim.x + threadIdx.x) >> 6;
    int lane = threadIdx.x & 63;
    if (wid >= N) return;
    int su = __builtin_amdgcn_readfirstlane(offs[wid]);
    int eu = __builtin_amdgcn_readfirstlane(offs[wid + 1]);
    int dl = 2 * lane;
    const float2* hrow = (const float2*)hconv + lane;  // row r at hrow[r*64]
    float2 hme = *(const float2*)(hconv + wid * D + dl);
    if (su >= eu) {  // empty segment: m = 0
        *(float2*)(t + wid * D + dl) = hme;
        return;
    }
    constexpr float L2E = 1.4426950408889634f;
    float Mx = -INFINITY, My = -INFINITY;
    float Sx = 0.f, Sy = 0.f, Wx = 0.f, Wy = 0.f;

    int4 ra = recs[su];
    float2 ha = hrow[ra.x * 64];
    int i1 = (su + 1 < eu) ? su + 1 : su;
    int4 rb = recs[i1];
    float2 hb = hrow[rb.x * 64];

    int e = su;
    for (; e + 1 < eu; e += 2) {
        int i2 = (e + 2 < eu) ? e + 2 : su;  // clamped prefetch (dummy = first edge)
        int i3 = (e + 3 < eu) ? e + 3 : su;
        int4 rna = recs[i2];
        int4 rnb = recs[i3];
        float2 hna = hrow[rna.x * 64];
        float2 hnb = hrow[rnb.x * 64];

        float2 a0 = *(const float2*)(sb + ra.y * D + dl);
        float2 a1 = *(const float2*)(sb + 1024 + ra.z * D + dl);
        float2 a2 = *(const float2*)(sb + 2048 + ra.w * D + dl);
        float vax = fmaxf(ha.x + a0.x + a1.x + a2.x, 0.f) + 1e-7f;
        float vay = fmaxf(ha.y + a0.y + a1.y + a2.y, 0.f) + 1e-7f;
        float2 b0 = *(const float2*)(sb + rb.y * D + dl);
        float2 b1 = *(const float2*)(sb + 1024 + rb.z * D + dl);
        float2 b2 = *(const float2*)(sb + 2048 + rb.w * D + dl);
        float vbx = fmaxf(hb.x + b0.x + b1.x + b2.x, 0.f) + 1e-7f;
        float vby = fmaxf(hb.y + b0.y + b1.y + b2.y, 0.f) + 1e-7f;

        float uax = vax * L2E, uay = vay * L2E;
        float ubx = vbx * L2E, uby = vby * L2E;

        // shared-max online update, base-2 domain (3 exps per 2 edges)
        float nMx = fmaxf(Mx, fmaxf(uax, ubx));
        float cx  = __builtin_amdgcn_exp2f(Mx - nMx);
        float pax = __builtin_amdgcn_exp2f(uax - nMx);
        float pbx = __builtin_amdgcn_exp2f(ubx - nMx);
        Sx = fmaf(Sx, cx, pax + pbx);
        Wx = fmaf(Wx, cx, fmaf(pax, vax, pbx * vbx));
        Mx = nMx;

        float nMy = fmaxf(My, fmaxf(uay, uby));
        float cy  = __builtin_amdgcn_exp2f(My - nMy);
        float pay = __builtin_amdgcn_exp2f(uay - nMy);
        float pby = __builtin_amdgcn_exp2f(uby - nMy);
        Sy = fmaf(Sy, cy, pay + pby);
        Wy = fmaf(Wy, cy, fmaf(pay, vay, pby * vby));
        My = nMy;

        ra = rna; ha = hna; rb = rnb; hb = hnb;
    }
    if (e < eu) {  // odd tail: edge e is in (ra, ha)
        float2 a0 = *(const float2*)(sb + ra.y * D + dl);
        float2 a1 = *(const float2*)(sb + 1024 + ra.z * D + dl);
        float2 a2 = *(const float2*)(sb + 2048 + ra.w * D + dl);
        float vax = fmaxf(ha.x + a0.x + a1.x + a2.x, 0.f) + 1e-7f;
        float vay = fmaxf(ha.y + a0.y + a1.y + a2.y, 0.f) + 1e-7f;
        float uax = vax * L2E, uay = vay * L2E;
        float nMx = fmaxf(Mx, uax);
        float cx  = __builtin_amdgcn_exp2f(Mx - nMx);
        float pax = __builtin_amdgcn_exp2f(uax - nMx);
        Sx = fmaf(Sx, cx, pax);
        Wx = fmaf(Wx, cx, pax * vax);
        float nMy = fmaxf(My, uay);
        float cy  = __builtin_amdgcn_exp2f(My - nMy);
        float pay = __builtin_amdgcn_exp2f(uay - nMy);
        Sy = fmaf(Sy, cy, pay);
        Wy = fmaf(Wy, cy, pay * vay);
    }
    float mx = Wx / (Sx + 1e-16f);
    float my = Wy / (Sy + 1e-16f);
    *(float2*)(t + wid * D + dl) = make_float2(hme.x + mx, hme.y + my);
}

// ------------------------- GEMM + fused LN(+ReLU) -------------------------
// outh = A @ W + b (+ res); hc = LN(outh)*g+beta [ReLU opt].
// 64-node tile, 256 threads, 4x8 micro-tile. Row lives across 16 lanes of
// one wave -> shfl_xor reduction for LN mean/var.

template <int RELU>
__global__ __launch_bounds__(256) void k_gemm(const float* __restrict__ A,
                                              const float* __restrict__ Wl,
                                              const float* __restrict__ bl,
                                              const float* __restrict__ res,
                                              float* __restrict__ outh,
                                              const float* __restrict__ g,
                                              const float* __restrict__ bta,
                                              float* __restrict__ hc,
                                              int N, int useRes) {
    __shared__ float As[64 * 36];   // [m][k] padded stride 36
    __shared__ float Bs[32 * 128];  // [k][j]
    int tid = threadIdx.x;
    int tx = tid & 15;   // j-group: dims tx*8 .. tx*8+7
    int ty = tid >> 4;   // m-group: rows ty + 16*i, i=0..3
    int m0 = blockIdx.x * 64;

    float acc[4][8];
#pragma unroll
    for (int i = 0; i < 4; ++i)
#pragma unroll
        for (int j = 0; j < 8; ++j) acc[i][j] = 0.f;

    for (int kk0 = 0; kk0 < 128; kk0 += 32) {
#pragma unroll
        for (int it = 0; it < 2; ++it) {  // stage A chunk: 64x32
            int lin = it * 256 + tid;
            int node = lin >> 3, kq = lin & 7;
            int gm = m0 + node;
            float4 va = (gm < N) ? *(const float4*)(A + gm * 128 + kk0 + kq * 4)
                                 : make_float4(0.f, 0.f, 0.f, 0.f);
            *(float4*)(As + node * 36 + kq * 4) = va;
        }
#pragma unroll
        for (int it = 0; it < 4; ++it) {  // stage B chunk: 32x128
            int lin = it * 256 + tid;
            int k = lin >> 5, jq = lin & 31;
            *(float4*)(Bs + k * 128 + jq * 4) = *(const float4*)(Wl + (kk0 + k) * 128 + jq * 4);
        }
        __syncthreads();
#pragma unroll
        for (int kk = 0; kk < 32; ++kk) {
            float4 b0 = *(const float4*)(Bs + kk * 128 + tx * 8);
            float4 b1 = *(const float4*)(Bs + kk * 128 + tx * 8 + 4);
            float av[4];
#pragma unroll
            for (int i = 0; i < 4; ++i) av[i] = As[(ty + 16 * i) * 36 + kk];
#pragma unroll
            for (int i = 0; i < 4; ++i) {
                float a = av[i];
                acc[i][0] = fmaf(a, b0.x, acc[i][0]);
                acc[i][1] = fmaf(a, b0.y, acc[i][1]);
                acc[i][2] = fmaf(a, b0.z, acc[i][2]);
                acc[i][3] = fmaf(a, b0.w, acc[i][3]);
                acc[i][4] = fmaf(a, b1.x, acc[i][4]);
                acc[i][5] = fmaf(a, b1.y, acc[i][5]);
                acc[i][6] = fmaf(a, b1.z, acc[i][6]);
                acc[i][7] = fmaf(a, b1.w, acc[i][7]);
            }
        }
        __syncthreads();
    }

    float4 bb0 = *(const float4*)(bl + tx * 8);
    float4 bb1 = *(const float4*)(bl + tx * 8 + 4);
    float4 gg0 = *(const float4*)(g + tx * 8);
    float4 gg1 = *(const float4*)(g + tx * 8 + 4);
    float4 bt0 = *(const float4*)(bta + tx * 8);
    float4 bt1 = *(const float4*)(bta + tx * 8 + 4);
#pragma unroll
    for (int i = 0; i < 4; ++i) {
        int gm = m0 + ty + 16 * i;
        bool ok = gm < N;
        float o[8];
#pragma unroll
        for (int j = 0; j < 8; ++j) o[j] = acc[i][j];
        o[0] += bb0.x; o[1] += bb0.y; o[2] += bb0.z; o[3] += bb0.w;
        o[4] += bb1.x; o[5] += bb1.y; o[6] += bb1.z; o[7] += bb1.w;
        if (useRes && ok) {
            float4 r0 = *(const float4*)(res + gm * 128 + tx * 8);
            float4 r1 = *(const float4*)(res + gm * 128 + tx * 8 + 4);
            o[0] += r0.x; o[1] += r0.y; o[2] += r0.z; o[3] += r0.w;
            o[4] += r1.x; o[5] += r1.y; o[6] += r1.z; o[7] += r1.w;
        }
        if (ok) {
            *(float4*)(outh + gm * 128 + tx * 8) = make_float4(o[0], o[1], o[2], o[3]);
            *(float4*)(outh + gm * 128 + tx * 8 + 4) = make_float4(o[4], o[5], o[6], o[7]);
        }
        // LN across the 16-lane tx group (same wave)
        float s = 0.f, ss = 0.f;
#pragma unroll
        for (int j = 0; j < 8; ++j) { s += o[j]; ss += o[j] * o[j]; }
#pragma unroll
        for (int off = 1; off < 16; off <<= 1) {
            s += __shfl_xor(s, off, 64);
            ss += __shfl_xor(ss, off, 64);
        }
        float mu = s * (1.f / 128.f);
        float var = ss * (1.f / 128.f) - mu * mu;
        float rs = rsqrtf(var + 1e-5f);
        float l[8];
        l[0] = (o[0] - mu) * rs * gg0.x + bt0.x;
        l[1] = (o[1] - mu) * rs * gg0.y + bt0.y;
        l[2] = (o[2] - mu) * rs * gg0.z + bt0.z;
        l[3] = (o[3] - mu) * rs * gg0.w + bt0.w;
        l[4] = (o[4] - mu) * rs * gg1.x + bt1.x;
        l[5] = (o[5] - mu) * rs * gg1.y + bt1.y;
        l[6] = (o[6] - mu) * rs * gg1.z + bt1.z;
        l[7] = (o[7] - mu) * rs * gg1.w + bt1.w;
        if (RELU) {
#pragma unroll
            for (int j = 0; j < 8; ++j) l[j] = fmaxf(l[j], 0.f);
        }
        if (ok) {
            *(float4*)(hc + gm * 128 + tx * 8) = make_float4(l[0], l[1], l[2], l[3]);
            *(float4*)(hc + gm * 128 + tx * 8 + 4) = make_float4(l[4], l[5], l[6], l[7]);
        }
    }
}

// ------------------------- Launch -------------------------

extern "C" void kernel_launch(void* const* d_in, const int* in_sizes, int n_in,
                              void* d_out, int out_size, void* d_ws, size_t ws_size,
                              hipStream_t stream) {
    const int*   x    = (const int*)d_in[0];
    const int*   ei   = (const int*)d_in[1];
    const int*   attr = (const int*)d_in[2];
    const float* aemb = (const float*)d_in[3];
    const float* bemb = (const float*)d_in[4];
    const float* Wf   = (const float*)d_in[5];
    const float* bf   = (const float*)d_in[6];
    const float* gam  = (const float*)d_in[7];
    const float* bet  = (const float*)d_in[8];
    float* out = (float*)d_out;

    const int N = in_sizes[0] / NA;        // 50000
    const int E = in_sizes[1] / 2;         // 625000
    const int L = in_sizes[5] / (D * D);   // 7

    char* ws = (char*)d_ws;
    size_t o = 0;
    auto carve = [&](size_t bytes) -> void* {
        void* p = (void*)(ws + o);
        o += (bytes + 255) & ~(size_t)255;
        return p;
    };
    float* h     = (float*)carve((size_t)N * D * 4);
    float* hconv = (float*)carve((size_t)N * D * 4);
    float* t     = (float*)carve((size_t)N * D * 4);
    int4*  recs  = (int4*)carve((size_t)E * 16);
    int*   deg   = (int*)carve((size_t)N * 4);
    int*   cur   = (int*)carve((size_t)N * 4);
    int*   offs  = (int*)carve((size_t)(N + 1) * 4);
    int*   bsum  = (int*)carve(4096);
    int*   bexc  = (int*)carve(4096);

    const int* src = ei;
    const int* dst = ei + E;

    hipMemsetAsync(deg, 0, (size_t)N * 4, stream);
    hipMemsetAsync(cur, 0, (size_t)N * 4, stream);

    int ebl = (E + 255) / 256;
    int nbl = (N + 255) / 256;  // 196 (<=256 required by k_scan_b)
    k_hist<<<ebl, 256, 0, stream>>>(dst, deg, E);
    k_scan_a<<<nbl, 256, 0, stream>>>(deg, offs, bsum, N);
    k_scan_b<<<1, 256, 0, stream>>>(bsum, bexc, nbl);
    k_scan_c<<<nbl, 256, 0, stream>>>(offs, bexc, N);
    k_fill<<<ebl, 256, 0, stream>>>(src, dst, attr, offs, cur, recs, E);

    int wbl = (N * 64 + 255) / 256;  // wave per node, 4 waves/block (k_atom)
    k_atom<<<wbl, 256, 0, stream>>>(x, aemb, h, N);

    int abl = (N + 15) / 16;   // k_agg: 16 nodes per 1024-thread block
    int gbl = (N + 63) / 64;   // k_gemm: 64-node tiles
    for (int l = 0; l < L; ++l) {
        const float* hc_in = (l == 0) ? h : hconv;
        k_agg<<<abl, 1024, 0, stream>>>(hc_in, recs, offs, bemb, t, N);
        // gemm_l writes h_l and fused LN(gamma[l]) -> hconv (ReLU) or out (final)
        if (l == L - 1) {
            k_gemm<0><<<gbl, 256, 0, stream>>>(t, Wf + l * D * D, bf + l * D, h, h,
                                               gam + l * D, bet + l * D, out, N, l > 0 ? 1 : 0);
        } else {
            k_gemm<1><<<gbl, 256, 0, stream>>>(t, Wf + l * D * D, bf + l * D, h, h,
                                               gam + l * D, bet + l * D, hconv, N, l > 0 ? 1 : 0);
        }
    }
}

// Round 3
// 778.632 us; speedup vs baseline: 1.5476x; 1.0832x over previous
//
#include <hip/hip_runtime.h>
#include <math.h>

// DeeperGCN on MI355X. N=50000, E=625000, D=128, L=7.
// CSR-by-dst build per call; online-softmax single-pass aggregation
// (wave per node, 4-edge unroll, -inf-masked dummy slots, scalar record
// loads); fp32 register-tiled GEMM with fused LayerNorm(+ReLU) epilogue.

constexpr int D = 128;
constexpr int NA = 9;   // atom feats
constexpr int NB = 3;   // bond feats

// ------------------------- CSR build -------------------------

__global__ void k_hist(const int* __restrict__ dst, int* __restrict__ deg, int E) {
    int e = blockIdx.x * 256 + threadIdx.x;
    if (e < E) atomicAdd(&deg[dst[e]], 1);
}

__global__ void k_scan_a(const int* __restrict__ deg, int* __restrict__ offs,
                         int* __restrict__ bsum, int N) {
    __shared__ int s[256];
    int i = blockIdx.x * 256 + threadIdx.x;
    int v = (i < N) ? deg[i] : 0;
    s[threadIdx.x] = v;
    __syncthreads();
    for (int d = 1; d < 256; d <<= 1) {
        int add = (threadIdx.x >= d) ? s[threadIdx.x - d] : 0;
        __syncthreads();
        s[threadIdx.x] += add;
        __syncthreads();
    }
    if (i < N) offs[i + 1] = s[threadIdx.x];
    if (threadIdx.x == 255) bsum[blockIdx.x] = s[255];
    if (i == 0) offs[0] = 0;
}

// nb must be <= 256 (N=50000 -> nb=196)
__global__ void k_scan_b(const int* __restrict__ bsum, int* __restrict__ bexc, int nb) {
    __shared__ int s[256];
    int t = threadIdx.x;
    int v = (t < nb) ? bsum[t] : 0;
    s[t] = v;
    __syncthreads();
    for (int d = 1; d < 256; d <<= 1) {
        int add = (t >= d) ? s[t - d] : 0;
        __syncthreads();
        s[t] += add;
        __syncthreads();
    }
    if (t < nb) bexc[t] = s[t] - v;  // exclusive block prefix
}

__global__ void k_scan_c(int* __restrict__ offs, const int* __restrict__ bexc, int N) {
    int i = blockIdx.x * 256 + threadIdx.x;
    if (i < N) offs[i + 1] += bexc[blockIdx.x];
}

__global__ void k_fill(const int* __restrict__ src, const int* __restrict__ dst,
                       const int* __restrict__ attr, const int* __restrict__ offs,
                       int* __restrict__ cur, int4* __restrict__ recs, int E) {
    int e = blockIdx.x * 256 + threadIdx.x;
    if (e >= E) return;
    int d = dst[e];
    int pos = offs[d] + atomicAdd(&cur[d], 1);
    recs[pos] = make_int4(src[e], attr[e * 3], attr[e * 3 + 1], attr[e * 3 + 2]);
}

// ------------------------- Atom encoder -------------------------
// wave per node; lane holds d = 2*lane, 2*lane+1

__global__ void k_atom(const int* __restrict__ x, const float* __restrict__ aemb,
                       float* __restrict__ h, int N) {
    int wid = (blockIdx.x * blockDim.x + threadIdx.x) >> 6;
    int lane = threadIdx.x & 63;
    if (wid >= N) return;
    const int* xr = x + wid * NA;
    float ax = 0.f, ay = 0.f;
#pragma unroll
    for (int f = 0; f < NA; ++f) {
        int v = xr[f];  // wave-uniform broadcast
        const float2 e = *(const float2*)(aemb + (f * 64 + v) * D + 2 * lane);
        ax += e.x; ay += e.y;
    }
    *(float2*)(h + wid * D + 2 * lane) = make_float2(ax, ay);
}

// ------------------------- Aggregation (online softmax, 4-edge unroll) ----
// wave per node; t[n] = hconv[n] + m[n]. Block = 512 (8 nodes).
// Edge records scalar-loaded at uniform clamped indices; invalid slots are
// masked by forcing their base-2 logit to -inf (p=0), so no tail code and
// no divergence.

__global__ __launch_bounds__(512) void k_agg(const float* __restrict__ hconv,
                      const int4* __restrict__ recs,
                      const int* __restrict__ offs, const float* __restrict__ bemb,
                      float* __restrict__ t, int N) {
    __shared__ float sb[NB * 8 * D];  // 3072 floats = 12 KB
    {
        const float4* b4 = (const float4*)bemb;
        float4* s4 = (float4*)sb;
        for (int i = threadIdx.x; i < NB * 8 * D / 4; i += 512) s4[i] = b4[i];
    }
    __syncthreads();
    int wid = (blockIdx.x * blockDim.x + threadIdx.x) >> 6;
    int lane = threadIdx.x & 63;
    if (wid >= N) return;
    int su = __builtin_amdgcn_readfirstlane(offs[wid]);
    int eu = __builtin_amdgcn_readfirstlane(offs[wid + 1]);
    int dl = 2 * lane;
    const float2* hrow = (const float2*)hconv + lane;  // row r at hrow[r*64]
    float2 hme = *(const float2*)(hconv + wid * D + dl);
    if (su >= eu) {  // empty segment: m = 0
        *(float2*)(t + wid * D + dl) = hme;
        return;
    }
    constexpr float L2E = 1.4426950408889634f;
    float Mx = -INFINITY, My = -INFINITY;
    float Sx = 0.f, Sy = 0.f, Wx = 0.f, Wy = 0.f;

    int last = eu - 1;
    int4 r[4];
    float2 hh[4];
#pragma unroll
    for (int i = 0; i < 4; ++i) {
        int idx = su + i; idx = (idx < last) ? idx : last;
        r[i] = recs[idx];
        hh[i] = hrow[r[i].x * 64];
    }

    for (int e = su; e < eu; e += 4) {
        int4 nr[4]; float2 nh[4];
#pragma unroll
        for (int i = 0; i < 4; ++i) {  // prefetch next group (clamped)
            int idx = e + 4 + i; idx = (idx < last) ? idx : last;
            nr[i] = recs[idx];
            nh[i] = hrow[nr[i].x * 64];
        }
        float vx[4], vy[4], ux[4], uy[4];
#pragma unroll
        for (int i = 0; i < 4; ++i) {
            float2 b0 = *(const float2*)(sb + r[i].y * D + dl);
            float2 b1 = *(const float2*)(sb + 1024 + r[i].z * D + dl);
            float2 b2 = *(const float2*)(sb + 2048 + r[i].w * D + dl);
            vx[i] = fmaxf(hh[i].x + b0.x + b1.x + b2.x, 0.f) + 1e-7f;
            vy[i] = fmaxf(hh[i].y + b0.y + b1.y + b2.y, 0.f) + 1e-7f;
            bool valid = (e + i) < eu;  // uniform condition
            ux[i] = valid ? vx[i] * L2E : -INFINITY;
            uy[i] = valid ? vy[i] * L2E : -INFINITY;
        }
        // shared-max online update, base-2 domain (5 exps per 4 edges / comp)
        float nMx = fmaxf(fmaxf(Mx, fmaxf(ux[0], ux[1])), fmaxf(ux[2], ux[3]));
        float cx = __builtin_amdgcn_exp2f(Mx - nMx);
        float p0 = __builtin_amdgcn_exp2f(ux[0] - nMx);
        float p1 = __builtin_amdgcn_exp2f(ux[1] - nMx);
        float p2 = __builtin_amdgcn_exp2f(ux[2] - nMx);
        float p3 = __builtin_amdgcn_exp2f(ux[3] - nMx);
        Sx = fmaf(Sx, cx, (p0 + p1) + (p2 + p3));
        float wsum = fmaf(p0, vx[0], p1 * vx[1]) + fmaf(p2, vx[2], p3 * vx[3]);
        Wx = fmaf(Wx, cx, wsum);
        Mx = nMx;

        float nMy = fmaxf(fmaxf(My, fmaxf(uy[0], uy[1])), fmaxf(uy[2], uy[3]));
        float cy = __builtin_amdgcn_exp2f(My - nMy);
        float q0 = __builtin_amdgcn_exp2f(uy[0] - nMy);
        float q1 = __builtin_amdgcn_exp2f(uy[1] - nMy);
        float q2 = __builtin_amdgcn_exp2f(uy[2] - nMy);
        float q3 = __builtin_amdgcn_exp2f(uy[3] - nMy);
        Sy = fmaf(Sy, cy, (q0 + q1) + (q2 + q3));
        float wsumy = fmaf(q0, vy[0], q1 * vy[1]) + fmaf(q2, vy[2], q3 * vy[3]);
        Wy = fmaf(Wy, cy, wsumy);
        My = nMy;

#pragma unroll
        for (int i = 0; i < 4; ++i) { r[i] = nr[i]; hh[i] = nh[i]; }
    }
    float mx = Wx / (Sx + 1e-16f);
    float my = Wy / (Sy + 1e-16f);
    *(float2*)(t + wid * D + dl) = make_float2(hme.x + mx, hme.y + my);
}

// ------------------------- GEMM + fused LN(+ReLU) -------------------------
// outh = A @ W + b (+ res); hc = LN(outh)*g+beta [ReLU opt].
// 64-node tile, 256 threads, 4x8 micro-tile. Row lives across 16 lanes of
// one wave -> shfl_xor reduction for LN mean/var.

template <int RELU>
__global__ __launch_bounds__(256) void k_gemm(const float* __restrict__ A,
                                              const float* __restrict__ Wl,
                                              const float* __restrict__ bl,
                                              const float* __restrict__ res,
                                              float* __restrict__ outh,
                                              const float* __restrict__ g,
                                              const float* __restrict__ bta,
                                              float* __restrict__ hc,
                                              int N, int useRes) {
    __shared__ float As[64 * 36];   // [m][k] padded stride 36
    __shared__ float Bs[32 * 128];  // [k][j]
    int tid = threadIdx.x;
    int tx = tid & 15;   // j-group: dims tx*8 .. tx*8+7
    int ty = tid >> 4;   // m-group: rows ty + 16*i, i=0..3
    int m0 = blockIdx.x * 64;

    float acc[4][8];
#pragma unroll
    for (int i = 0; i < 4; ++i)
#pragma unroll
        for (int j = 0; j < 8; ++j) acc[i][j] = 0.f;

    for (int kk0 = 0; kk0 < 128; kk0 += 32) {
#pragma unroll
        for (int it = 0; it < 2; ++it) {  // stage A chunk: 64x32
            int lin = it * 256 + tid;
            int node = lin >> 3, kq = lin & 7;
            int gm = m0 + node;
            float4 va = (gm < N) ? *(const float4*)(A + gm * 128 + kk0 + kq * 4)
                                 : make_float4(0.f, 0.f, 0.f, 0.f);
            *(float4*)(As + node * 36 + kq * 4) = va;
        }
#pragma unroll
        for (int it = 0; it < 4; ++it) {  // stage B chunk: 32x128
            int lin = it * 256 + tid;
            int k = lin >> 5, jq = lin & 31;
            *(float4*)(Bs + k * 128 + jq * 4) = *(const float4*)(Wl + (kk0 + k) * 128 + jq * 4);
        }
        __syncthreads();
#pragma unroll
        for (int kk = 0; kk < 32; ++kk) {
            float4 b0 = *(const float4*)(Bs + kk * 128 + tx * 8);
            float4 b1 = *(const float4*)(Bs + kk * 128 + tx * 8 + 4);
            float av[4];
#pragma unroll
            for (int i = 0; i < 4; ++i) av[i] = As[(ty + 16 * i) * 36 + kk];
#pragma unroll
            for (int i = 0; i < 4; ++i) {
                float a = av[i];
                acc[i][0] = fmaf(a, b0.x, acc[i][0]);
                acc[i][1] = fmaf(a, b0.y, acc[i][1]);
                acc[i][2] = fmaf(a, b0.z, acc[i][2]);
                acc[i][3] = fmaf(a, b0.w, acc[i][3]);
                acc[i][4] = fmaf(a, b1.x, acc[i][4]);
                acc[i][5] = fmaf(a, b1.y, acc[i][5]);
                acc[i][6] = fmaf(a, b1.z, acc[i][6]);
                acc[i][7] = fmaf(a, b1.w, acc[i][7]);
            }
        }
        __syncthreads();
    }

    float4 bb0 = *(const float4*)(bl + tx * 8);
    float4 bb1 = *(const float4*)(bl + tx * 8 + 4);
    float4 gg0 = *(const float4*)(g + tx * 8);
    float4 gg1 = *(const float4*)(g + tx * 8 + 4);
    float4 bt0 = *(const float4*)(bta + tx * 8);
    float4 bt1 = *(const float4*)(bta + tx * 8 + 4);
#pragma unroll
    for (int i = 0; i < 4; ++i) {
        int gm = m0 + ty + 16 * i;
        bool ok = gm < N;
        float o[8];
#pragma unroll
        for (int j = 0; j < 8; ++j) o[j] = acc[i][j];
        o[0] += bb0.x; o[1] += bb0.y; o[2] += bb0.z; o[3] += bb0.w;
        o[4] += bb1.x; o[5] += bb1.y; o[6] += bb1.z; o[7] += bb1.w;
        if (useRes && ok) {
            float4 r0 = *(const float4*)(res + gm * 128 + tx * 8);
            float4 r1 = *(const float4*)(res + gm * 128 + tx * 8 + 4);
            o[0] += r0.x; o[1] += r0.y; o[2] += r0.z; o[3] += r0.w;
            o[4] += r1.x; o[5] += r1.y; o[6] += r1.z; o[7] += r1.w;
        }
        if (ok) {
            *(float4*)(outh + gm * 128 + tx * 8) = make_float4(o[0], o[1], o[2], o[3]);
            *(float4*)(outh + gm * 128 + tx * 8 + 4) = make_float4(o[4], o[5], o[6], o[7]);
        }
        // LN across the 16-lane tx group (same wave)
        float s = 0.f, ss = 0.f;
#pragma unroll
        for (int j = 0; j < 8; ++j) { s += o[j]; ss += o[j] * o[j]; }
#pragma unroll
        for (int off = 1; off < 16; off <<= 1) {
            s += __shfl_xor(s, off, 64);
            ss += __shfl_xor(ss, off, 64);
        }
        float mu = s * (1.f / 128.f);
        float var = ss * (1.f / 128.f) - mu * mu;
        float rs = rsqrtf(var + 1e-5f);
        float l[8];
        l[0] = (o[0] - mu) * rs * gg0.x + bt0.x;
        l[1] = (o[1] - mu) * rs * gg0.y + bt0.y;
        l[2] = (o[2] - mu) * rs * gg0.z + bt0.z;
        l[3] = (o[3] - mu) * rs * gg0.w + bt0.w;
        l[4] = (o[4] - mu) * rs * gg1.x + bt1.x;
        l[5] = (o[5] - mu) * rs * gg1.y + bt1.y;
        l[6] = (o[6] - mu) * rs * gg1.z + bt1.z;
        l[7] = (o[7] - mu) * rs * gg1.w + bt1.w;
        if (RELU) {
#pragma unroll
            for (int j = 0; j < 8; ++j) l[j] = fmaxf(l[j], 0.f);
        }
        if (ok) {
            *(float4*)(hc + gm * 128 + tx * 8) = make_float4(l[0], l[1], l[2], l[3]);
            *(float4*)(hc + gm * 128 + tx * 8 + 4) = make_float4(l[4], l[5], l[6], l[7]);
        }
    }
}

// ------------------------- Launch -------------------------

extern "C" void kernel_launch(void* const* d_in, const int* in_sizes, int n_in,
                              void* d_out, int out_size, void* d_ws, size_t ws_size,
                              hipStream_t stream) {
    const int*   x    = (const int*)d_in[0];
    const int*   ei   = (const int*)d_in[1];
    const int*   attr = (const int*)d_in[2];
    const float* aemb = (const float*)d_in[3];
    const float* bemb = (const float*)d_in[4];
    const float* Wf   = (const float*)d_in[5];
    const float* bf   = (const float*)d_in[6];
    const float* gam  = (const float*)d_in[7];
    const float* bet  = (const float*)d_in[8];
    float* out = (float*)d_out;

    const int N = in_sizes[0] / NA;        // 50000
    const int E = in_sizes[1] / 2;         // 625000
    const int L = in_sizes[5] / (D * D);   // 7

    char* ws = (char*)d_ws;
    size_t o = 0;
    auto carve = [&](size_t bytes) -> void* {
        void* p = (void*)(ws + o);
        o += (bytes + 255) & ~(size_t)255;
        return p;
    };
    float* h     = (float*)carve((size_t)N * D * 4);
    float* hconv = (float*)carve((size_t)N * D * 4);
    float* t     = (float*)carve((size_t)N * D * 4);
    int4*  recs  = (int4*)carve((size_t)E * 16);
    int*   deg   = (int*)carve((size_t)N * 4);
    int*   cur   = (int*)carve((size_t)N * 4);
    int*   offs  = (int*)carve((size_t)(N + 1) * 4);
    int*   bsum  = (int*)carve(4096);
    int*   bexc  = (int*)carve(4096);

    const int* src = ei;
    const int* dst = ei + E;

    hipMemsetAsync(deg, 0, (size_t)N * 4, stream);
    hipMemsetAsync(cur, 0, (size_t)N * 4, stream);

    int ebl = (E + 255) / 256;
    int nbl = (N + 255) / 256;  // 196 (<=256 required by k_scan_b)
    k_hist<<<ebl, 256, 0, stream>>>(dst, deg, E);
    k_scan_a<<<nbl, 256, 0, stream>>>(deg, offs, bsum, N);
    k_scan_b<<<1, 256, 0, stream>>>(bsum, bexc, nbl);
    k_scan_c<<<nbl, 256, 0, stream>>>(offs, bexc, N);
    k_fill<<<ebl, 256, 0, stream>>>(src, dst, attr, offs, cur, recs, E);

    int wbl = (N * 64 + 255) / 256;  // wave per node, 4 waves/block (k_atom)
    k_atom<<<wbl, 256, 0, stream>>>(x, aemb, h, N);

    int abl = (N + 7) / 8;     // k_agg: 8 nodes per 512-thread block
    int gbl = (N + 63) / 64;   // k_gemm: 64-node tiles
    for (int l = 0; l < L; ++l) {
        const float* hc_in = (l == 0) ? h : hconv;
        k_agg<<<abl, 512, 0, stream>>>(hc_in, recs, offs, bemb, t, N);
        // gemm_l writes h_l and fused LN(gamma[l]) -> hconv (ReLU) or out (final)
        if (l == L - 1) {
            k_gemm<0><<<gbl, 256, 0, stream>>>(t, Wf + l * D * D, bf + l * D, h, h,
                                               gam + l * D, bet + l * D, out, N, l > 0 ? 1 : 0);
        } else {
            k_gemm<1><<<gbl, 256, 0, stream>>>(t, Wf + l * D * D, bf + l * D, h, h,
                                               gam + l * D, bet + l * D, hconv, N, l > 0 ? 1 : 0);
        }
    }
}